// Round 1
// baseline (9834.422 us; speedup 1.0000x reference)
//
#include <hip/hip_runtime.h>

#define Bz 32
#define Tz 64
#define Sz 128
#define Dz 256
#define Vz 32000

__device__ __forceinline__ float sigmf(float x){ return 1.0f/(1.0f + __expf(-x)); }
__device__ __forceinline__ float tanhfast(float x){ float e = __expf(2.0f*x); return 1.0f - 2.0f/(e+1.0f); }

// ---------------- K0: transpose Wx(512x1024), Wh(256x1024) -> W2T[1024][768] ----------------
__global__ void k_transpose(const float* __restrict__ Wx, const float* __restrict__ Wh,
                            float* __restrict__ W2T){
  __shared__ float tile[64][65];
  const int kt = blockIdx.x;   // 0..11
  const int jt = blockIdx.y;   // 0..15
  const int tid = threadIdx.x;
  const int lo = tid & 63;
  const int hi = tid >> 6;     // 0..3
  #pragma unroll
  for (int rr = 0; rr < 16; ++rr){
    int kl = rr*4 + hi;
    int k  = kt*64 + kl;
    int j  = jt*64 + lo;
    float v = (k < 512) ? Wx[k*1024 + j] : Wh[(k-512)*1024 + j];
    tile[kl][lo] = v;
  }
  __syncthreads();
  #pragma unroll
  for (int rr = 0; rr < 16; ++rr){
    int jl = rr*4 + hi;
    int kl = lo;
    W2T[(jt*64 + jl)*768 + kt*64 + kl] = tile[kl][jl];
  }
}

// ---------------- K1: keys = enc_out @ Wk + bk  ([32,128,256]); also reset barrier ----------------
__global__ void k_keys(const float* __restrict__ enc, const float* __restrict__ Wk,
                       const float* __restrict__ bk, float* __restrict__ keys,
                       unsigned* __restrict__ barcnt){
  const int blk = blockIdx.x;   // 256 blocks = 32 b x 8 s-chunks
  const int tid = threadIdx.x;  // 256
  if (blk == 0 && tid == 0) barcnt[0] = 0u;
  const int b  = blk >> 3;
  const int s0 = (blk & 7) * 16;
  const float* ebase = enc + (b*Sz + s0)*Dz;
  const int d = tid;
  float acc[16];
  #pragma unroll
  for (int i = 0; i < 16; ++i) acc[i] = 0.f;
  for (int k = 0; k < Dz; k += 4){
    float w0 = Wk[(k+0)*Dz + d];
    float w1 = Wk[(k+1)*Dz + d];
    float w2 = Wk[(k+2)*Dz + d];
    float w3 = Wk[(k+3)*Dz + d];
    #pragma unroll
    for (int si = 0; si < 16; ++si){
      float4 ev = *(const float4*)(ebase + si*Dz + k);   // uniform -> scalar loads
      acc[si] += ev.x*w0 + ev.y*w1 + ev.z*w2 + ev.w*w3;
    }
  }
  const float bkd = bk[d];
  #pragma unroll
  for (int si = 0; si < 16; ++si)
    keys[(b*Sz + s0 + si)*Dz + d] = acc[si] + bkd;
}

// ---------------- device-scope grid barrier (all blocks co-resident: 128 blocks on 256 CUs) ----------------
__device__ __forceinline__ void gbar(unsigned* cnt, unsigned target){
  __threadfence();
  __syncthreads();
  if (threadIdx.x == 0){
    __hip_atomic_fetch_add(cnt, 1u, __ATOMIC_ACQ_REL, __HIP_MEMORY_SCOPE_AGENT);
    while (__hip_atomic_load(cnt, __ATOMIC_ACQUIRE, __HIP_MEMORY_SCOPE_AGENT) < target){
      __builtin_amdgcn_s_sleep(2);
    }
  }
  __syncthreads();
  __threadfence();
}

// ---------------- K2: full recurrence, 64 steps inside one kernel ----------------
// grid 128 x 512. Phase1 (blocks 0..31): attention for batch row b -> xbuf[b][512]=ctx||emb
// Phase2 (all 128 blocks): z = [x||h] @ W2T^T (+b), gates, h/c update. Block = (bh in 0..1) x (rr in 0..63):
//   covers b in [16*bh,16*bh+16), units u in [4*rr, 4*rr+4), all 4 gates.
__global__ void __launch_bounds__(512) k_recur(
    const int* __restrict__ tok, const float* __restrict__ h0, const float* __restrict__ c0,
    const float* __restrict__ enc, const float* __restrict__ Emb,
    const float* __restrict__ Wq, const float* __restrict__ bq,
    const float* __restrict__ Vw, const float* __restrict__ bv,
    const float* __restrict__ bl, const float* __restrict__ keys,
    const float* __restrict__ W2T,
    float* __restrict__ xbuf, float* __restrict__ cbuf, float* __restrict__ hs,
    unsigned* __restrict__ barcnt)
{
  const int tid  = threadIdx.x;
  const int blk  = blockIdx.x;
  const unsigned nblk = gridDim.x;

  __shared__ float xh[16*772];   // 16 rows x 768 (padded to 772): [x(512) || h(256)]
  __shared__ float zp[2048];     // partials: [kk(8)][bb(16)][uu(4)][g(4)]
  __shared__ float hq[Dz];
  __shared__ float qv[Dz];
  __shared__ float red2[2*Dz];
  __shared__ float scp[Sz*4];
  __shared__ float se[Sz+1];

  for (int t = 0; t < Tz; ++t){
    // ---------- phase 1: attention ----------
    if (blk < Bz){
      const int b = blk;
      const float* hsrc = (t == 0) ? (h0 + b*Dz) : (hs + ((t-1)*Bz + b)*Dz);
      if (tid < Dz) hq[tid] = hsrc[tid];
      __syncthreads();
      { // q = h @ Wq + bq
        int d = tid & (Dz-1); int half = tid >> 8;
        const float* wp = Wq + (half*128)*Dz + d;
        const float* hp = hq + half*128;
        float a = 0.f;
        #pragma unroll 8
        for (int k = 0; k < 128; ++k) a = __builtin_fmaf(hp[k], wp[k*Dz], a);
        red2[half*Dz + d] = a;
      }
      __syncthreads();
      if (tid < Dz) qv[tid] = red2[tid] + red2[Dz+tid] + bq[tid];
      __syncthreads();
      { // scores
        int s = tid >> 2, dg = tid & 3;
        const float* kp = keys + (b*Sz + s)*Dz + dg*64;
        const float* qp = qv + dg*64;
        const float* vp = Vw + dg*64;
        float a = 0.f;
        #pragma unroll 4
        for (int k = 0; k < 64; ++k) a += tanhfast(qp[k] + kp[k]) * vp[k];
        scp[s*4 + dg] = a;
      }
      __syncthreads();
      if (tid < Sz){
        float sc = scp[tid*4] + scp[tid*4+1] + scp[tid*4+2] + scp[tid*4+3] + bv[0];
        se[tid] = __expf(sc);   // scores bounded (|score| <~ few) -> safe without max-sub
      }
      __syncthreads();
      if (tid < 64){
        float v = se[tid] + se[tid+64];
        #pragma unroll
        for (int off = 32; off > 0; off >>= 1) v += __shfl_down(v, off);
        if (tid == 0) se[Sz] = 1.0f / v;
      }
      __syncthreads();
      { // ctx and emb -> xbuf
        float inv = se[Sz];
        int d = tid & (Dz-1); int sh = tid >> 8;
        const float* ep = enc + (b*Sz + sh*64)*Dz + d;
        const float* ap = se + sh*64;
        float a = 0.f;
        #pragma unroll 8
        for (int s2 = 0; s2 < 64; ++s2) a = __builtin_fmaf(ap[s2], ep[s2*Dz], a);
        red2[sh*Dz + d] = a;
        __syncthreads();
        if (tid < Dz){
          xbuf[b*512 + tid] = (red2[tid] + red2[Dz+tid]) * inv;
        } else {
          int dd = tid - Dz;
          int tk = tok[b*Tz + t];
          xbuf[b*512 + Dz + dd] = Emb[tk*Dz + dd];
        }
      }
    }
    gbar(barcnt, (unsigned)(2*t+1) * nblk);

    // ---------- phase 2: gate GEMM + LSTM update ----------
    {
      const int bh = blk >> 6;   // 0..1
      const int rr = blk & 63;   // 0..63
      const float* hbase = (t == 0) ? h0 : (hs + (t-1)*Bz*Dz);
      #pragma unroll
      for (int i = 0; i < 6; ++i){ // stage x||h for 16 batch rows into LDS
        int f4 = tid + i*512;             // 0..3071
        int bb = f4 / 192; int kq = f4 - bb*192; int k = kq*4;
        int b  = bh*16 + bb;
        float4 v;
        if (k < 512) v = *(const float4*)(xbuf + b*512 + k);
        else         v = *(const float4*)(hbase + b*Dz + (k-512));
        *(float4*)(xh + bb*772 + k) = v;
      }
      __syncthreads();
      const int kk = tid >> 6;         // 0..7  (wave-uniform: k-slice per wave)
      const int bb = (tid >> 2) & 15;  // 0..15
      const int uu = tid & 3;          // 0..3
      const int jb = rr*4 + uu;        // unit
      float a0 = 0.f, a1 = 0.f, a2 = 0.f, a3 = 0.f;
      const float* xr  = xh + bb*772;
      const float* w0p = W2T + (0*Dz + jb)*768;
      const float* w1p = W2T + (1*Dz + jb)*768;
      const float* w2p = W2T + (2*Dz + jb)*768;
      const float* w3p = W2T + (3*Dz + jb)*768;
      #pragma unroll 6
      for (int i = 0; i < 24; ++i){
        int k = (kk + 8*i)*4;
        float4 xv  = *(const float4*)(xr  + k);
        float4 wv0 = *(const float4*)(w0p + k);
        float4 wv1 = *(const float4*)(w1p + k);
        float4 wv2 = *(const float4*)(w2p + k);
        float4 wv3 = *(const float4*)(w3p + k);
        a0 += xv.x*wv0.x + xv.y*wv0.y + xv.z*wv0.z + xv.w*wv0.w;
        a1 += xv.x*wv1.x + xv.y*wv1.y + xv.z*wv1.z + xv.w*wv1.w;
        a2 += xv.x*wv2.x + xv.y*wv2.y + xv.z*wv2.z + xv.w*wv2.w;
        a3 += xv.x*wv3.x + xv.y*wv3.y + xv.z*wv3.z + xv.w*wv3.w;
      }
      *(float4*)(zp + kk*256 + bb*16 + uu*4) = make_float4(a0, a1, a2, a3);
      __syncthreads();
      if (tid < 64){
        const int bb2 = tid >> 2, u2 = tid & 3;
        float z4[4] = {0.f, 0.f, 0.f, 0.f};
        #pragma unroll
        for (int k2 = 0; k2 < 8; ++k2){
          float4 zv = *(const float4*)(zp + k2*256 + bb2*16 + u2*4);
          z4[0] += zv.x; z4[1] += zv.y; z4[2] += zv.z; z4[3] += zv.w;
        }
        const int b = bh*16 + bb2;
        const int u = rr*4 + u2;
        float zi = z4[0] + bl[0*Dz + u];
        float zf = z4[1] + bl[1*Dz + u];
        float zg = z4[2] + bl[2*Dz + u];
        float zo = z4[3] + bl[3*Dz + u];
        float cold = (t == 0) ? c0[b*Dz + u] : cbuf[((t-1)&1)*Bz*Dz + b*Dz + u];
        float cn = sigmf(zf)*cold + sigmf(zi)*tanhfast(zg);
        float hn = sigmf(zo)*tanhfast(cn);
        cbuf[(t&1)*Bz*Dz + b*Dz + u] = cn;
        hs[(t*Bz + b)*Dz + u] = hn;
      }
    }
    gbar(barcnt, (unsigned)(2*t+2) * nblk);
  }
}

// ---------------- K3: exp(logits) -> out ; per-(colblock,row) partial sums -> part ----------------
// grid (125, 32), 256 thr. Block: cols j = bx*256+tid, rows R0..R0+64 (R = t*32+b, hs order).
__global__ void __launch_bounds__(256) k_logits(
    const float* __restrict__ hs, const float* __restrict__ Wo, const float* __restrict__ bo,
    float* __restrict__ out, float* __restrict__ part)
{
  __shared__ float rsum[64*4];
  const int tid = threadIdx.x;
  const int j   = blockIdx.x*256 + tid;   // < 32000
  const int R0  = blockIdx.y*64;
  float acc[64];
  #pragma unroll
  for (int r = 0; r < 64; ++r) acc[r] = 0.f;
  const float* hp = hs + R0*Dz;
  for (int k = 0; k < Dz; k += 4){
    float w0 = Wo[(size_t)(k+0)*Vz + j];
    float w1 = Wo[(size_t)(k+1)*Vz + j];
    float w2 = Wo[(size_t)(k+2)*Vz + j];
    float w3 = Wo[(size_t)(k+3)*Vz + j];
    #pragma unroll
    for (int r = 0; r < 64; ++r){
      float4 hv = *(const float4*)(hp + r*Dz + k);   // uniform -> scalar loads
      acc[r] = __builtin_fmaf(hv.x, w0, acc[r]);
      acc[r] = __builtin_fmaf(hv.y, w1, acc[r]);
      acc[r] = __builtin_fmaf(hv.z, w2, acc[r]);
      acc[r] = __builtin_fmaf(hv.w, w3, acc[r]);
    }
  }
  const float boj = bo[j];
  const int wid = tid >> 6, lane = tid & 63;
  #pragma unroll
  for (int r = 0; r < 64; ++r){
    int R = R0 + r;
    int tt = R >> 5, b = R & 31;
    float p = __expf(acc[r] + boj);
    out[(size_t)(b*Tz + tt)*Vz + j] = p;
    float v = p;
    #pragma unroll
    for (int off = 32; off > 0; off >>= 1) v += __shfl_down(v, off);
    if (lane == 0) rsum[r*4 + wid] = v;
  }
  __syncthreads();
  if (tid < 64){
    float s = rsum[tid*4] + rsum[tid*4+1] + rsum[tid*4+2] + rsum[tid*4+3];
    part[(size_t)blockIdx.x*2048 + R0 + tid] = s;   // deterministic (no float atomics)
  }
}

// ---------------- K3b: sums[R] = sum over 125 column blocks ----------------
__global__ void k_rowsum(const float* __restrict__ part, float* __restrict__ sums){
  const int R = blockIdx.x*256 + threadIdx.x;
  if (R < 2048){
    float s = 0.f;
    for (int c = 0; c < 125; ++c) s += part[(size_t)c*2048 + R];
    sums[R] = s;
  }
}

// ---------------- K4: out *= 1/sum (in place) ----------------
__global__ void k_scale(float* __restrict__ out, const float* __restrict__ sums){
  const int row = blockIdx.y;              // out-row = b*64 + t
  const int b = row >> 6, tt = row & 63;
  const float inv = 1.0f / sums[tt*Bz + b];
  const int j = (blockIdx.x*256 + threadIdx.x) * 4;
  if (j < Vz){
    float4* p = (float4*)(out + (size_t)row*Vz + j);
    float4 v = *p;
    v.x *= inv; v.y *= inv; v.z *= inv; v.w *= inv;
    *p = v;
  }
}

extern "C" void kernel_launch(void* const* d_in, const int* in_sizes, int n_in,
                              void* d_out, int out_size, void* d_ws, size_t ws_size,
                              hipStream_t stream){
  const int*   tok = (const int*)  d_in[0];
  const float* h0  = (const float*)d_in[1];
  const float* c0  = (const float*)d_in[2];
  const float* enc = (const float*)d_in[3];
  const float* E   = (const float*)d_in[4];
  const float* Wq  = (const float*)d_in[5];
  const float* bq  = (const float*)d_in[6];
  const float* Wk  = (const float*)d_in[7];
  const float* bk  = (const float*)d_in[8];
  const float* Vw  = (const float*)d_in[9];
  const float* bv  = (const float*)d_in[10];
  const float* Wx  = (const float*)d_in[11];
  const float* Wh  = (const float*)d_in[12];
  const float* bl  = (const float*)d_in[13];
  const float* Wo  = (const float*)d_in[14];
  const float* bo  = (const float*)d_in[15];
  float* out = (float*)d_out;
  float* ws  = (float*)d_ws;

  float* keys  = ws;                       // 1,048,576 f
  float* W2T   = keys + 1048576;           //   786,432 f
  float* xbuf  = W2T  + 786432;            //    16,384 f
  float* cbuf  = xbuf + 16384;             //    16,384 f
  float* hs    = cbuf + 16384;             //   524,288 f
  float* part  = hs   + 524288;            //   256,000 f
  float* sums  = part + 256000;            //     2,048 f
  unsigned* barcnt = (unsigned*)(sums + 2048);

  hipLaunchKernelGGL(k_transpose, dim3(12,16), dim3(256), 0, stream, Wx, Wh, W2T);
  hipLaunchKernelGGL(k_keys, dim3(256), dim3(256), 0, stream, enc, Wk, bk, keys, barcnt);
  hipLaunchKernelGGL(k_recur, dim3(128), dim3(512), 0, stream,
                     tok, h0, c0, enc, E, Wq, bq, Vw, bv, bl, keys, W2T,
                     xbuf, cbuf, hs, barcnt);
  hipLaunchKernelGGL(k_logits, dim3(125,32), dim3(256), 0, stream, hs, Wo, bo, out, part);
  hipLaunchKernelGGL(k_rowsum, dim3(8), dim3(256), 0, stream, part, sums);
  hipLaunchKernelGGL(k_scale, dim3(32,2048), dim3(256), 0, stream, out, sums);
}

// Round 2
// 4723.916 us; speedup vs baseline: 2.0818x; 2.0818x over previous
//
#include <hip/hip_runtime.h>

#define Bz 32
#define Tz 64
#define Sz 128
#define Dz 256
#define Vz 32000

__device__ __forceinline__ float sigmf(float x){ return 1.0f/(1.0f + __expf(-x)); }
__device__ __forceinline__ float tanhfast(float x){ float e = __expf(2.0f*x); return 1.0f - 2.0f/(e+1.0f); }

// ---------------- K0: transpose Wx(512x1024), Wh(256x1024) -> W2T[1024][768] ----------------
__global__ void k_transpose(const float* __restrict__ Wx, const float* __restrict__ Wh,
                            float* __restrict__ W2T){
  __shared__ float tile[64][65];
  const int kt = blockIdx.x;   // 0..11
  const int jt = blockIdx.y;   // 0..15
  const int tid = threadIdx.x;
  const int lo = tid & 63;
  const int hi = tid >> 6;     // 0..3
  #pragma unroll
  for (int rr = 0; rr < 16; ++rr){
    int kl = rr*4 + hi;
    int k  = kt*64 + kl;
    int j  = jt*64 + lo;
    float v = (k < 512) ? Wx[k*1024 + j] : Wh[(k-512)*1024 + j];
    tile[kl][lo] = v;
  }
  __syncthreads();
  #pragma unroll
  for (int rr = 0; rr < 16; ++rr){
    int jl = rr*4 + hi;
    int kl = lo;
    W2T[(jt*64 + jl)*768 + kt*64 + kl] = tile[kl][jl];
  }
}

// ---------------- K1: keys = enc_out @ Wk + bk  ([32,128,256]); also reset flags ----------------
__global__ void k_keys(const float* __restrict__ enc, const float* __restrict__ Wk,
                       const float* __restrict__ bk, float* __restrict__ keys,
                       unsigned* __restrict__ flags){
  const int blk = blockIdx.x;   // 256 blocks = 32 b x 8 s-chunks
  const int tid = threadIdx.x;  // 256
  if (blk == 0 && tid < 128) flags[tid] = 0u;   // reset barrier flags (kernel-boundary makes it visible)
  const int b  = blk >> 3;
  const int s0 = (blk & 7) * 16;
  const float* ebase = enc + (b*Sz + s0)*Dz;
  const int d = tid;
  float acc[16];
  #pragma unroll
  for (int i = 0; i < 16; ++i) acc[i] = 0.f;
  for (int k = 0; k < Dz; k += 4){
    float w0 = Wk[(k+0)*Dz + d];
    float w1 = Wk[(k+1)*Dz + d];
    float w2 = Wk[(k+2)*Dz + d];
    float w3 = Wk[(k+3)*Dz + d];
    #pragma unroll
    for (int si = 0; si < 16; ++si){
      float4 ev = *(const float4*)(ebase + si*Dz + k);
      acc[si] += ev.x*w0 + ev.y*w1 + ev.z*w2 + ev.w*w3;
    }
  }
  const float bkd = bk[d];
  #pragma unroll
  for (int si = 0; si < 16; ++si)
    keys[(b*Sz + s0 + si)*Dz + d] = acc[si] + bkd;
}

// ---------------- flag-array grid barrier ----------------
// arrive: one relaxed agent store to own slot (after a single release fence = L2 writeback).
// wait: lanes 0..nblk-1 poll DISTINCT flags with RELAXED agent loads (no cache-inv per poll!),
//       then ONE acquire fence (single buffer_inv) once all flags have arrived.
__device__ __forceinline__ void arrive_wait(unsigned* flags, unsigned nblk, unsigned token){
  __syncthreads();   // all waves' prior stores drained to L2 (syncthreads implies vmcnt drain)
  if (threadIdx.x == 0){
    __builtin_amdgcn_fence(__ATOMIC_RELEASE, "agent");   // flush this XCD's dirty L2 lines once
    __hip_atomic_store(flags + blockIdx.x, token, __ATOMIC_RELAXED, __HIP_MEMORY_SCOPE_AGENT);
  }
  if (threadIdx.x < nblk){
    while (__hip_atomic_load(flags + threadIdx.x, __ATOMIC_RELAXED, __HIP_MEMORY_SCOPE_AGENT) < token){
      __builtin_amdgcn_s_sleep(2);
    }
    __builtin_amdgcn_fence(__ATOMIC_ACQUIRE, "agent");   // one invalidate, not one per poll
  }
  __syncthreads();
}

// ---------------- K2: full recurrence, 64 steps inside one kernel ----------------
__global__ void __launch_bounds__(512) k_recur(
    const int* __restrict__ tok, const float* __restrict__ h0, const float* __restrict__ c0,
    const float* __restrict__ enc, const float* __restrict__ Emb,
    const float* __restrict__ Wq, const float* __restrict__ bq,
    const float* __restrict__ Vw, const float* __restrict__ bv,
    const float* __restrict__ bl, const float* __restrict__ keys,
    const float* __restrict__ W2T,
    float* __restrict__ xbuf, float* __restrict__ cbuf, float* __restrict__ hs,
    unsigned* __restrict__ flags)
{
  const int tid  = threadIdx.x;
  const int blk  = blockIdx.x;
  const unsigned nblk = gridDim.x;

  __shared__ float xh[16*772];   // 16 rows x 768 (padded to 772): [x(512) || h(256)]
  __shared__ float zp[2048];     // partials: [kk(8)][bb(16)][uu(4)][g(4)]
  __shared__ float hq[Dz];
  __shared__ float qv[Dz];
  __shared__ float red2[2*Dz];
  __shared__ float scp[Sz*4];
  __shared__ float se[Sz+1];

  for (int t = 0; t < Tz; ++t){
    // ---------- phase 1: attention ----------
    if (blk < Bz){
      const int b = blk;
      const float* hsrc = (t == 0) ? (h0 + b*Dz) : (hs + ((t-1)*Bz + b)*Dz);
      if (tid < Dz) hq[tid] = hsrc[tid];
      __syncthreads();
      { // q = h @ Wq + bq
        int d = tid & (Dz-1); int half = tid >> 8;
        const float* wp = Wq + (half*128)*Dz + d;
        const float* hp = hq + half*128;
        float a = 0.f;
        #pragma unroll 8
        for (int k = 0; k < 128; ++k) a = __builtin_fmaf(hp[k], wp[k*Dz], a);
        red2[half*Dz + d] = a;
      }
      __syncthreads();
      if (tid < Dz) qv[tid] = red2[tid] + red2[Dz+tid] + bq[tid];
      __syncthreads();
      { // scores
        int s = tid >> 2, dg = tid & 3;
        const float* kp = keys + (b*Sz + s)*Dz + dg*64;
        const float* qp = qv + dg*64;
        const float* vp = Vw + dg*64;
        float a = 0.f;
        #pragma unroll 4
        for (int k = 0; k < 64; ++k) a += tanhfast(qp[k] + kp[k]) * vp[k];
        scp[s*4 + dg] = a;
      }
      __syncthreads();
      if (tid < Sz){
        float sc = scp[tid*4] + scp[tid*4+1] + scp[tid*4+2] + scp[tid*4+3] + bv[0];
        se[tid] = __expf(sc);
      }
      __syncthreads();
      if (tid < 64){
        float v = se[tid] + se[tid+64];
        #pragma unroll
        for (int off = 32; off > 0; off >>= 1) v += __shfl_down(v, off);
        if (tid == 0) se[Sz] = 1.0f / v;
      }
      __syncthreads();
      { // ctx and emb -> xbuf
        float inv = se[Sz];
        int d = tid & (Dz-1); int sh = tid >> 8;
        const float* ep = enc + (b*Sz + sh*64)*Dz + d;
        const float* ap = se + sh*64;
        float a = 0.f;
        #pragma unroll 8
        for (int s2 = 0; s2 < 64; ++s2) a = __builtin_fmaf(ap[s2], ep[s2*Dz], a);
        red2[sh*Dz + d] = a;
        __syncthreads();
        if (tid < Dz){
          xbuf[b*512 + tid] = (red2[tid] + red2[Dz+tid]) * inv;
        } else {
          int dd = tid - Dz;
          int tk = tok[b*Tz + t];
          xbuf[b*512 + Dz + dd] = Emb[tk*Dz + dd];
        }
      }
    }
    arrive_wait(flags, nblk, (unsigned)(2*t+1));

    // ---------- phase 2: gate GEMM + LSTM update ----------
    {
      const int bh = blk >> 6;   // 0..1
      const int rr = blk & 63;   // 0..63
      const float* hbase = (t == 0) ? h0 : (hs + (t-1)*Bz*Dz);
      #pragma unroll
      for (int i = 0; i < 6; ++i){ // stage x||h for 16 batch rows into LDS
        int f4 = tid + i*512;             // 0..3071
        int bb = f4 / 192; int kq = f4 - bb*192; int k = kq*4;
        int b  = bh*16 + bb;
        float4 v;
        if (k < 512) v = *(const float4*)(xbuf + b*512 + k);
        else         v = *(const float4*)(hbase + b*Dz + (k-512));
        *(float4*)(xh + bb*772 + k) = v;
      }
      __syncthreads();
      const int kk = tid >> 6;         // 0..7
      const int bb = (tid >> 2) & 15;  // 0..15
      const int uu = tid & 3;          // 0..3
      const int jb = rr*4 + uu;        // unit
      float a0 = 0.f, a1 = 0.f, a2 = 0.f, a3 = 0.f;
      const float* xr  = xh + bb*772;
      const float* w0p = W2T + (0*Dz + jb)*768;
      const float* w1p = W2T + (1*Dz + jb)*768;
      const float* w2p = W2T + (2*Dz + jb)*768;
      const float* w3p = W2T + (3*Dz + jb)*768;
      #pragma unroll 6
      for (int i = 0; i < 24; ++i){
        int k = (kk + 8*i)*4;
        float4 xv  = *(const float4*)(xr  + k);
        float4 wv0 = *(const float4*)(w0p + k);
        float4 wv1 = *(const float4*)(w1p + k);
        float4 wv2 = *(const float4*)(w2p + k);
        float4 wv3 = *(const float4*)(w3p + k);
        a0 += xv.x*wv0.x + xv.y*wv0.y + xv.z*wv0.z + xv.w*wv0.w;
        a1 += xv.x*wv1.x + xv.y*wv1.y + xv.z*wv1.z + xv.w*wv1.w;
        a2 += xv.x*wv2.x + xv.y*wv2.y + xv.z*wv2.z + xv.w*wv2.w;
        a3 += xv.x*wv3.x + xv.y*wv3.y + xv.z*wv3.z + xv.w*wv3.w;
      }
      *(float4*)(zp + kk*256 + bb*16 + uu*4) = make_float4(a0, a1, a2, a3);
      __syncthreads();
      if (tid < 64){
        const int bb2 = tid >> 2, u2 = tid & 3;
        float z4[4] = {0.f, 0.f, 0.f, 0.f};
        #pragma unroll
        for (int k2 = 0; k2 < 8; ++k2){
          float4 zv = *(const float4*)(zp + k2*256 + bb2*16 + u2*4);
          z4[0] += zv.x; z4[1] += zv.y; z4[2] += zv.z; z4[3] += zv.w;
        }
        const int b = bh*16 + bb2;
        const int u = rr*4 + u2;
        float zi = z4[0] + bl[0*Dz + u];
        float zf = z4[1] + bl[1*Dz + u];
        float zg = z4[2] + bl[2*Dz + u];
        float zo = z4[3] + bl[3*Dz + u];
        float cold = (t == 0) ? c0[b*Dz + u] : cbuf[((t-1)&1)*Bz*Dz + b*Dz + u];
        float cn = sigmf(zf)*cold + sigmf(zi)*tanhfast(zg);
        float hn = sigmf(zo)*tanhfast(cn);
        cbuf[(t&1)*Bz*Dz + b*Dz + u] = cn;
        hs[(t*Bz + b)*Dz + u] = hn;
      }
    }
    arrive_wait(flags, nblk, (unsigned)(2*t+2));
  }
}

// ---------------- K3: exp(logits) -> out ; per-(colblock,row) partial sums -> part ----------------
// grid (125, 8), 256 thr. Block: cols j = bx*256+tid; rows by*256 .. +256 in 4 chunks of 64.
__global__ void __launch_bounds__(256) k_logits(
    const float* __restrict__ hs, const float* __restrict__ Wo, const float* __restrict__ bo,
    float* __restrict__ out, float* __restrict__ part)
{
  __shared__ float rsum[64*4];
  const int tid = threadIdx.x;
  const int j   = blockIdx.x*256 + tid;   // < 32000
  const float boj = bo[j];
  const int wid = tid >> 6, lane = tid & 63;

  for (int ch = 0; ch < 4; ++ch){
    const int R0 = blockIdx.y*256 + ch*64;
    float acc[64];
    #pragma unroll
    for (int r = 0; r < 64; ++r) acc[r] = 0.f;
    const float* hp = hs + (size_t)R0*Dz;
    for (int k = 0; k < Dz; k += 4){
      float w0 = Wo[(size_t)(k+0)*Vz + j];
      float w1 = Wo[(size_t)(k+1)*Vz + j];
      float w2 = Wo[(size_t)(k+2)*Vz + j];
      float w3 = Wo[(size_t)(k+3)*Vz + j];
      #pragma unroll
      for (int r = 0; r < 64; ++r){
        float4 hv = *(const float4*)(hp + r*Dz + k);   // wave-uniform -> scalar loads
        acc[r] = __builtin_fmaf(hv.x, w0, acc[r]);
        acc[r] = __builtin_fmaf(hv.y, w1, acc[r]);
        acc[r] = __builtin_fmaf(hv.z, w2, acc[r]);
        acc[r] = __builtin_fmaf(hv.w, w3, acc[r]);
      }
    }
    #pragma unroll
    for (int r = 0; r < 64; ++r){
      int R = R0 + r;
      int tt = R >> 5, b = R & 31;
      float p = __expf(acc[r] + boj);
      out[(size_t)(b*Tz + tt)*Vz + j] = p;
      float v = p;
      #pragma unroll
      for (int off = 32; off > 0; off >>= 1) v += __shfl_down(v, off);
      if (lane == 0) rsum[r*4 + wid] = v;
    }
    __syncthreads();
    if (tid < 64){
      float s = rsum[tid*4] + rsum[tid*4+1] + rsum[tid*4+2] + rsum[tid*4+3];
      part[(size_t)blockIdx.x*2048 + R0 + tid] = s;
    }
    __syncthreads();   // protect rsum reuse across chunks
  }
}

// ---------------- K3b: sums[R] = sum over 125 column blocks ----------------
__global__ void k_rowsum(const float* __restrict__ part, float* __restrict__ sums){
  const int R = blockIdx.x*256 + threadIdx.x;
  if (R < 2048){
    float s = 0.f;
    for (int c = 0; c < 125; ++c) s += part[(size_t)c*2048 + R];
    sums[R] = s;
  }
}

// ---------------- K4: out *= 1/sum (in place), one block per output row ----------------
__global__ void __launch_bounds__(256) k_scale(float* __restrict__ out, const float* __restrict__ sums){
  const int row = blockIdx.x;              // out-row = b*64 + t, 2048 rows
  const int b = row >> 6, tt = row & 63;
  const float inv = 1.0f / sums[tt*Bz + b];
  float4* rp = (float4*)(out + (size_t)row*Vz);
  for (int j4 = threadIdx.x; j4 < Vz/4; j4 += 256){
    float4 v = rp[j4];
    v.x *= inv; v.y *= inv; v.z *= inv; v.w *= inv;
    rp[j4] = v;
  }
}

extern "C" void kernel_launch(void* const* d_in, const int* in_sizes, int n_in,
                              void* d_out, int out_size, void* d_ws, size_t ws_size,
                              hipStream_t stream){
  const int*   tok = (const int*)  d_in[0];
  const float* h0  = (const float*)d_in[1];
  const float* c0  = (const float*)d_in[2];
  const float* enc = (const float*)d_in[3];
  const float* E   = (const float*)d_in[4];
  const float* Wq  = (const float*)d_in[5];
  const float* bq  = (const float*)d_in[6];
  const float* Wk  = (const float*)d_in[7];
  const float* bk  = (const float*)d_in[8];
  const float* Vw  = (const float*)d_in[9];
  const float* bv  = (const float*)d_in[10];
  const float* Wx  = (const float*)d_in[11];
  const float* Wh  = (const float*)d_in[12];
  const float* bl  = (const float*)d_in[13];
  const float* Wo  = (const float*)d_in[14];
  const float* bo  = (const float*)d_in[15];
  float* out = (float*)d_out;
  float* ws  = (float*)d_ws;

  float* keys  = ws;                       // 1,048,576 f
  float* W2T   = keys + 1048576;           //   786,432 f
  float* xbuf  = W2T  + 786432;            //    16,384 f
  float* cbuf  = xbuf + 16384;             //    16,384 f
  float* hs    = cbuf + 16384;             //   524,288 f
  float* part  = hs   + 524288;            //   256,000 f
  float* sums  = part + 256000;            //     2,048 f
  unsigned* flags = (unsigned*)(sums + 2048);  // 128 u32

  hipLaunchKernelGGL(k_transpose, dim3(12,16), dim3(256), 0, stream, Wx, Wh, W2T);
  hipLaunchKernelGGL(k_keys, dim3(256), dim3(256), 0, stream, enc, Wk, bk, keys, flags);
  hipLaunchKernelGGL(k_recur, dim3(128), dim3(512), 0, stream,
                     tok, h0, c0, enc, E, Wq, bq, Vw, bv, bl, keys, W2T,
                     xbuf, cbuf, hs, flags);
  hipLaunchKernelGGL(k_logits, dim3(125,8), dim3(256), 0, stream, hs, Wo, bo, out, part);
  hipLaunchKernelGGL(k_rowsum, dim3(8), dim3(256), 0, stream, part, sums);
  hipLaunchKernelGGL(k_scale, dim3(2048), dim3(256), 0, stream, out, sums);
}

// Round 3
// 3786.895 us; speedup vs baseline: 2.5970x; 1.2474x over previous
//
#include <hip/hip_runtime.h>

#define Bz 32
#define Tz 64
#define Sz 128
#define Dz 256
#define Vz 32000

__device__ __forceinline__ float sigmf(float x){ return 1.0f/(1.0f + __expf(-x)); }
__device__ __forceinline__ float tanhfast(float x){ float e = __expf(2.0f*x); return 1.0f - 2.0f/(e+1.0f); }

// ---------------- K1: keys = enc_out @ Wk + bk  ([32,128,256]) ----------------
__global__ void k_keys(const float* __restrict__ enc, const float* __restrict__ Wk,
                       const float* __restrict__ bk, float* __restrict__ keys){
  const int blk = blockIdx.x;   // 256 blocks = 32 b x 8 s-chunks
  const int tid = threadIdx.x;  // 256
  const int b  = blk >> 3;
  const int s0 = (blk & 7) * 16;
  const float* ebase = enc + (b*Sz + s0)*Dz;
  const int d = tid;
  float acc[16];
  #pragma unroll
  for (int i = 0; i < 16; ++i) acc[i] = 0.f;
  for (int k = 0; k < Dz; k += 4){
    float w0 = Wk[(k+0)*Dz + d];
    float w1 = Wk[(k+1)*Dz + d];
    float w2 = Wk[(k+2)*Dz + d];
    float w3 = Wk[(k+3)*Dz + d];
    #pragma unroll
    for (int si = 0; si < 16; ++si){
      float4 ev = *(const float4*)(ebase + si*Dz + k);
      acc[si] += ev.x*w0 + ev.y*w1 + ev.z*w2 + ev.w*w3;
    }
  }
  const float bkd = bk[d];
  #pragma unroll
  for (int si = 0; si < 16; ++si)
    keys[(b*Sz + s0 + si)*Dz + d] = acc[si] + bkd;
}

// ---------------- K2: full recurrence, one block per batch row, ZERO grid barriers ----------------
// 32 blocks x 1024 threads. h,c persist in LDS across all 64 steps; only __syncthreads().
__global__ void __launch_bounds__(1024) k_recur(
    const int* __restrict__ tok, const float* __restrict__ h0, const float* __restrict__ c0,
    const float* __restrict__ enc, const float* __restrict__ Emb,
    const float* __restrict__ Wq, const float* __restrict__ bq,
    const float* __restrict__ Vw, const float* __restrict__ bv,
    const float* __restrict__ Wx, const float* __restrict__ Wh,
    const float* __restrict__ bl, const float* __restrict__ keys,
    float* __restrict__ hs)
{
  const int b   = blockIdx.x;
  const int tid = threadIdx.x;

  __shared__ float hlds[Dz], clds[Dz], qv[Dz], vlds[Dz];
  __shared__ float xh[768];          // ctx(256) || emb(256) || h(256)
  __shared__ float part4[4*Dz];      // q / ctx partials
  __shared__ float scp[Sz];
  __shared__ float selds[Sz+1];
  __shared__ float zp[4*1024];       // gate-GEMM partials [kq][unit]

  if (tid < Dz){
    hlds[tid] = h0[b*Dz + tid];
    clds[tid] = c0[b*Dz + tid];
    vlds[tid] = Vw[tid];
  }
  __syncthreads();

  const int d8 = tid & 255;   // 0..255
  const int kq = tid >> 8;    // 0..3
  const int ss = tid >> 3;    // 0..127 (score row)
  const int p8 = tid & 7;     // 0..7   (score d-part)

  for (int t = 0; t < Tz; ++t){
    // ---- q = h @ Wq + bq (4 k-quarters of 64) ----
    {
      const float* wp = Wq + (kq*64)*Dz + d8;
      const float* hp = hlds + kq*64;
      float a = 0.f;
      #pragma unroll 8
      for (int k = 0; k < 64; ++k) a = __builtin_fmaf(hp[k], wp[k*Dz], a);
      part4[kq*Dz + d8] = a;
    }
    __syncthreads();
    if (tid < Dz) qv[tid] = part4[tid] + part4[Dz+tid] + part4[2*Dz+tid] + part4[3*Dz+tid] + bq[tid];
    __syncthreads();

    // ---- scores: 8 threads per s, each covers d = p8*4 + 32j (coalesced keys, conflict-free LDS) ----
    {
      const float* kp = keys + (size_t)(b*Sz + ss)*Dz;
      float a = 0.f;
      #pragma unroll
      for (int j = 0; j < 8; ++j){
        const int d0 = p8*4 + j*32;
        float4 kv = *(const float4*)(kp + d0);
        float4 qj = *(const float4*)(qv + d0);
        float4 vj = *(const float4*)(vlds + d0);
        a += tanhfast(qj.x + kv.x) * vj.x;
        a += tanhfast(qj.y + kv.y) * vj.y;
        a += tanhfast(qj.z + kv.z) * vj.z;
        a += tanhfast(qj.w + kv.w) * vj.w;
      }
      a += __shfl_down(a, 4);
      a += __shfl_down(a, 2);
      a += __shfl_down(a, 1);
      if (p8 == 0) scp[ss] = a;
    }
    __syncthreads();
    if (tid < Sz) selds[tid] = __expf(scp[tid] + bv[0]);   // scores bounded -> safe without max-sub
    __syncthreads();
    if (tid < 64){
      float v = selds[tid] + selds[tid+64];
      #pragma unroll
      for (int off = 32; off > 0; off >>= 1) v += __shfl_down(v, off);
      if (tid == 0) selds[Sz] = 1.0f / v;
    }
    __syncthreads();

    // ---- ctx partials (4 s-quarters of 32) ----
    {
      const float* ep = enc + (size_t)(b*Sz + kq*32)*Dz + d8;
      const float* ap = selds + kq*32;
      float a = 0.f;
      #pragma unroll 8
      for (int s = 0; s < 32; ++s) a = __builtin_fmaf(ap[s], ep[(size_t)s*Dz], a);
      part4[kq*Dz + d8] = a;
    }
    __syncthreads();
    if (tid < Dz){
      xh[tid] = (part4[tid] + part4[Dz+tid] + part4[2*Dz+tid] + part4[3*Dz+tid]) * selds[Sz];
    } else if (tid < 512){
      const int tk = tok[b*Tz + t];
      xh[tid] = Emb[(size_t)tk*Dz + (tid - Dz)];
    } else if (tid < 768){
      xh[tid] = hlds[tid - 512];    // h_{t-1}, updated only after the next sync barrier pair
    }
    __syncthreads();

    // ---- gate GEMM: thread (g=d8, kq) -> units 4g..4g+3, k-range [kq*192, kq*192+192) ----
    {
      const int g  = d8;
      const int k0 = kq*192, k1 = k0 + 192;
      float a0=0.f, a1=0.f, a2=0.f, a3=0.f;
      const int ke = (k1 < 512) ? k1 : 512;
      for (int k = k0; k < ke; k += 4){
        float4 xv = *(const float4*)(xh + k);
        float4 w0 = *(const float4*)(Wx + (size_t)(k+0)*1024 + 4*g);
        float4 w1 = *(const float4*)(Wx + (size_t)(k+1)*1024 + 4*g);
        float4 w2 = *(const float4*)(Wx + (size_t)(k+2)*1024 + 4*g);
        float4 w3 = *(const float4*)(Wx + (size_t)(k+3)*1024 + 4*g);
        a0 += xv.x*w0.x + xv.y*w1.x + xv.z*w2.x + xv.w*w3.x;
        a1 += xv.x*w0.y + xv.y*w1.y + xv.z*w2.y + xv.w*w3.y;
        a2 += xv.x*w0.z + xv.y*w1.z + xv.z*w2.z + xv.w*w3.z;
        a3 += xv.x*w0.w + xv.y*w1.w + xv.z*w2.w + xv.w*w3.w;
      }
      const int kb = (k0 > 512) ? k0 : 512;
      for (int k = kb; k < k1; k += 4){
        float4 xv = *(const float4*)(xh + k);
        float4 w0 = *(const float4*)(Wh + (size_t)(k-512+0)*1024 + 4*g);
        float4 w1 = *(const float4*)(Wh + (size_t)(k-512+1)*1024 + 4*g);
        float4 w2 = *(const float4*)(Wh + (size_t)(k-512+2)*1024 + 4*g);
        float4 w3 = *(const float4*)(Wh + (size_t)(k-512+3)*1024 + 4*g);
        a0 += xv.x*w0.x + xv.y*w1.x + xv.z*w2.x + xv.w*w3.x;
        a1 += xv.x*w0.y + xv.y*w1.y + xv.z*w2.y + xv.w*w3.y;
        a2 += xv.x*w0.z + xv.y*w1.z + xv.z*w2.z + xv.w*w3.z;
        a3 += xv.x*w0.w + xv.y*w1.w + xv.z*w2.w + xv.w*w3.w;
      }
      *(float4*)(zp + kq*1024 + 4*g) = make_float4(a0, a1, a2, a3);
    }
    __syncthreads();

    // ---- LSTM update (threads 0..255) ----
    if (tid < Dz){
      const int u = tid;
      float zi = bl[u], zf = bl[Dz+u], zg = bl[2*Dz+u], zo = bl[3*Dz+u];
      #pragma unroll
      for (int q2 = 0; q2 < 4; ++q2){
        zi += zp[q2*1024 + u];
        zf += zp[q2*1024 + Dz + u];
        zg += zp[q2*1024 + 2*Dz + u];
        zo += zp[q2*1024 + 3*Dz + u];
      }
      float cold = clds[u];
      float cn = sigmf(zf)*cold + sigmf(zi)*tanhfast(zg);
      float hn = sigmf(zo)*tanhfast(cn);
      clds[u] = cn;
      hlds[u] = hn;
      hs[(size_t)(t*Bz + b)*Dz + u] = hn;
    }
    __syncthreads();
  }
}

// ---------------- K3: exp(logits) -> out ; per-(colblock,row) partial sums -> part ----------------
// grid (125, 8), 256 thr. Block: cols j = bx*256+tid; rows by*256 .. +256 in 4 chunks of 64.
__global__ void __launch_bounds__(256) k_logits(
    const float* __restrict__ hs, const float* __restrict__ Wo, const float* __restrict__ bo,
    float* __restrict__ out, float* __restrict__ part)
{
  __shared__ float rsum[64*4];
  const int tid = threadIdx.x;
  const int j   = blockIdx.x*256 + tid;   // < 32000
  const float boj = bo[j];
  const int wid = tid >> 6, lane = tid & 63;

  for (int ch = 0; ch < 4; ++ch){
    const int R0 = blockIdx.y*256 + ch*64;
    float acc[64];
    #pragma unroll
    for (int r = 0; r < 64; ++r) acc[r] = 0.f;
    const float* hp = hs + (size_t)R0*Dz;
    for (int k = 0; k < Dz; k += 4){
      float w0 = Wo[(size_t)(k+0)*Vz + j];
      float w1 = Wo[(size_t)(k+1)*Vz + j];
      float w2 = Wo[(size_t)(k+2)*Vz + j];
      float w3 = Wo[(size_t)(k+3)*Vz + j];
      #pragma unroll
      for (int r = 0; r < 64; ++r){
        float4 hv = *(const float4*)(hp + r*Dz + k);   // wave-uniform -> scalar loads
        acc[r] = __builtin_fmaf(hv.x, w0, acc[r]);
        acc[r] = __builtin_fmaf(hv.y, w1, acc[r]);
        acc[r] = __builtin_fmaf(hv.z, w2, acc[r]);
        acc[r] = __builtin_fmaf(hv.w, w3, acc[r]);
      }
    }
    #pragma unroll
    for (int r = 0; r < 64; ++r){
      int R = R0 + r;
      int tt = R >> 5, b = R & 31;
      float p = __expf(acc[r] + boj);
      out[(size_t)(b*Tz + tt)*Vz + j] = p;
      float v = p;
      #pragma unroll
      for (int off = 32; off > 0; off >>= 1) v += __shfl_down(v, off);
      if (lane == 0) rsum[r*4 + wid] = v;
    }
    __syncthreads();
    if (tid < 64){
      float s = rsum[tid*4] + rsum[tid*4+1] + rsum[tid*4+2] + rsum[tid*4+3];
      part[(size_t)blockIdx.x*2048 + R0 + tid] = s;
    }
    __syncthreads();
  }
}

// ---------------- K4: row-sum (fused) + out *= 1/sum, one block per output row ----------------
__global__ void __launch_bounds__(256) k_scale(float* __restrict__ out, const float* __restrict__ part){
  const int row = blockIdx.x;              // out-row = b*64 + t, 2048 rows
  const int b = row >> 6, tt = row & 63;
  const int R = tt*Bz + b;                 // hs-order row index
  const int tid = threadIdx.x;
  __shared__ float ssum[4];
  float v = (tid < 125) ? part[(size_t)tid*2048 + R] : 0.f;
  #pragma unroll
  for (int off = 32; off > 0; off >>= 1) v += __shfl_down(v, off);
  if ((tid & 63) == 0) ssum[tid >> 6] = v;
  __syncthreads();
  const float inv = 1.0f / (ssum[0] + ssum[1] + ssum[2] + ssum[3]);
  float4* rp = (float4*)(out + (size_t)row*Vz);
  for (int j4 = tid; j4 < Vz/4; j4 += 256){
    float4 x = rp[j4];
    x.x *= inv; x.y *= inv; x.z *= inv; x.w *= inv;
    rp[j4] = x;
  }
}

extern "C" void kernel_launch(void* const* d_in, const int* in_sizes, int n_in,
                              void* d_out, int out_size, void* d_ws, size_t ws_size,
                              hipStream_t stream){
  const int*   tok = (const int*)  d_in[0];
  const float* h0  = (const float*)d_in[1];
  const float* c0  = (const float*)d_in[2];
  const float* enc = (const float*)d_in[3];
  const float* E   = (const float*)d_in[4];
  const float* Wq  = (const float*)d_in[5];
  const float* bq  = (const float*)d_in[6];
  const float* Wk  = (const float*)d_in[7];
  const float* bk  = (const float*)d_in[8];
  const float* Vw  = (const float*)d_in[9];
  const float* bv  = (const float*)d_in[10];
  const float* Wx  = (const float*)d_in[11];
  const float* Wh  = (const float*)d_in[12];
  const float* bl  = (const float*)d_in[13];
  const float* Wo  = (const float*)d_in[14];
  const float* bo  = (const float*)d_in[15];
  float* out = (float*)d_out;
  float* ws  = (float*)d_ws;

  float* keys = ws;                  // 1,048,576 f
  float* hs   = keys + 1048576;      //   524,288 f
  float* part = hs   + 524288;       //   256,000 f

  hipLaunchKernelGGL(k_keys, dim3(256), dim3(256), 0, stream, enc, Wk, bk, keys);
  hipLaunchKernelGGL(k_recur, dim3(32), dim3(1024), 0, stream,
                     tok, h0, c0, enc, E, Wq, bq, Vw, bv, Wx, Wh, bl, keys, hs);
  hipLaunchKernelGGL(k_logits, dim3(125,8), dim3(256), 0, stream, hs, Wo, bo, out, part);
  hipLaunchKernelGGL(k_scale, dim3(2048), dim3(256), 0, stream, out, part);
}

// Round 4
// 2124.344 us; speedup vs baseline: 4.6294x; 1.7826x over previous
//
#include <hip/hip_runtime.h>

#define Bz 32
#define Tz 64
#define Sz 128
#define Dz 256
#define Vz 32000

__device__ __forceinline__ float sigmf(float x){ return 1.0f/(1.0f + __expf(-x)); }
__device__ __forceinline__ float tanhfast(float x){ float e = __expf(2.0f*x); return 1.0f - 2.0f/(e+1.0f); }

// ---------------- K1: keys = enc_out @ Wk + bk  ([32,128,256]) ----------------
__global__ void k_keys(const float* __restrict__ enc, const float* __restrict__ Wk,
                       const float* __restrict__ bk, float* __restrict__ keys){
  const int blk = blockIdx.x;   // 256 blocks = 32 b x 8 s-chunks
  const int tid = threadIdx.x;  // 256
  const int b  = blk >> 3;
  const int s0 = (blk & 7) * 16;
  const float* ebase = enc + (b*Sz + s0)*Dz;
  const int d = tid;
  float acc[16];
  #pragma unroll
  for (int i = 0; i < 16; ++i) acc[i] = 0.f;
  for (int k = 0; k < Dz; k += 4){
    float w0 = Wk[(k+0)*Dz + d];
    float w1 = Wk[(k+1)*Dz + d];
    float w2 = Wk[(k+2)*Dz + d];
    float w3 = Wk[(k+3)*Dz + d];
    #pragma unroll
    for (int si = 0; si < 16; ++si){
      float4 ev = *(const float4*)(ebase + si*Dz + k);
      acc[si] += ev.x*w0 + ev.y*w1 + ev.z*w2 + ev.w*w3;
    }
  }
  const float bkd = bk[d];
  #pragma unroll
  for (int si = 0; si < 16; ++si)
    keys[(b*Sz + s0 + si)*Dz + d] = acc[si] + bkd;
}

// ---------------- K1b: encW[b*128+s][1024] = enc[b,s,:] @ Wx[0:256,:]  (+ flag reset) --------
__global__ void __launch_bounds__(256) k_encw(const float* __restrict__ enc,
                                              const float* __restrict__ Wx,
                                              float* __restrict__ encW,
                                              unsigned* flags){
  const int tid = threadIdx.x;
  if (blockIdx.x == 0) flags[tid] = 0u;     // reset barrier flags (256 entries)
  const int row0 = blockIdx.x * 4;          // 1024 blocks x 4 rows = 4096 rows
  const int u4 = tid * 4;
  float4 a0 = {0,0,0,0}, a1 = {0,0,0,0}, a2 = {0,0,0,0}, a3 = {0,0,0,0};
  for (int d = 0; d < Dz; ++d){
    float4 wv = *(const float4*)(Wx + (size_t)d*1024 + u4);
    float e0 = enc[(size_t)(row0+0)*Dz + d];
    float e1 = enc[(size_t)(row0+1)*Dz + d];
    float e2 = enc[(size_t)(row0+2)*Dz + d];
    float e3 = enc[(size_t)(row0+3)*Dz + d];
    a0.x += e0*wv.x; a0.y += e0*wv.y; a0.z += e0*wv.z; a0.w += e0*wv.w;
    a1.x += e1*wv.x; a1.y += e1*wv.y; a1.z += e1*wv.z; a1.w += e1*wv.w;
    a2.x += e2*wv.x; a2.y += e2*wv.y; a2.z += e2*wv.z; a2.w += e2*wv.w;
    a3.x += e3*wv.x; a3.y += e3*wv.y; a3.z += e3*wv.z; a3.w += e3*wv.w;
  }
  *(float4*)(encW + (size_t)(row0+0)*1024 + u4) = a0;
  *(float4*)(encW + (size_t)(row0+1)*1024 + u4) = a1;
  *(float4*)(encW + (size_t)(row0+2)*1024 + u4) = a2;
  *(float4*)(encW + (size_t)(row0+3)*1024 + u4) = a3;
}

// ---------------- K2: recurrence. 256 blocks = 32 rows x 8 unit-slices, 1024 thr ----------------
// Block (b, s): owns h-units [32s,32s+32) i.e. gate rows {g*256+32s+u}. Gate weights for
// k in [emb||h] (512) live in 64 regs/thread; ctx contribution via precomputed encW.
// One exchange per step: {q-partial(256) = h_slice @ Wq-slice, h_slice(32)} through L2/L3,
// r2-proven release-fence / relaxed-poll / acquire-fence flag protocol. blk%8==b%8 keeps a
// row's 8 slices on one XCD (perf heuristic only; protocol is agent-scope correct anyway).
__global__ void __launch_bounds__(1024) k_recur(
    const int* __restrict__ tok, const float* __restrict__ h0, const float* __restrict__ c0,
    const float* __restrict__ Emb,
    const float* __restrict__ Wq, const float* __restrict__ bq,
    const float* __restrict__ Vw, const float* __restrict__ bv,
    const float* __restrict__ Wx, const float* __restrict__ Wh,
    const float* __restrict__ bl, const float* __restrict__ keys,
    const float* __restrict__ encW,
    float* __restrict__ hs, float* xch, unsigned* flags)
{
  const int tid = threadIdx.x;
  const int blk = blockIdx.x;
  const int b = ((blk >> 6) << 3) | (blk & 7);   // row
  const int s = (blk >> 3) & 7;                  // unit-slice

  __shared__ float xe[512];        // [emb(256) || h(256)]
  __shared__ float qv[Dz];
  __shared__ float vl[Dz];
  __shared__ float scp[Sz];
  __shared__ float selds[Sz+1];
  __shared__ float zp[1024];       // [kc(8)][u_local(128)]
  __shared__ float zl[128];
  __shared__ float hnl[32];
  __shared__ float clds[32];
  __shared__ float qpp[1024];      // [jc(4)][d(256)]

  const int u_local = tid & 127;
  const int kc = tid >> 7;                                   // 0..7
  const int u_gate = ((u_local >> 5) << 8) + (s << 5) + (u_local & 31);
  const int dq = tid & 255;                                  // q-part d
  const int jc = tid >> 8;                                   // 0..3

  // --- one-time loads ---
  float w[64];   // gate weights, k_x = kc*64+i over [emb(0..255)||h(256..511)]
  {
    const float* wbase = (kc < 4) ? (Wx + (size_t)(256 + kc*64)*1024 + u_gate)
                                  : (Wh + (size_t)((kc-4)*64)*1024 + u_gate);
    #pragma unroll
    for (int i = 0; i < 64; ++i) w[i] = wbase[(size_t)i*1024];
  }
  float wq[8];   // Wq rows [32s+jc*8 .. +8), col dq
  #pragma unroll
  for (int jj = 0; jj < 8; ++jj) wq[jj] = Wq[(size_t)(s*32 + jc*8 + jj)*Dz + dq];

  if (tid < Dz) vl[tid] = Vw[tid];
  if (tid < 32) clds[tid] = c0[b*Dz + s*32 + tid];

  // --- pre-exchange (t=0 inputs from h0) ---
  {
    float qp = 0.f;
    #pragma unroll
    for (int jj = 0; jj < 8; ++jj) qp += h0[b*Dz + s*32 + jc*8 + jj] * wq[jj];
    qpp[jc*256 + dq] = qp;
  }
  __syncthreads();
  {
    float* x0 = xch + (size_t)((b*8) + s)*288;   // parity 0
    if (tid < 256)      x0[tid] = qpp[tid] + qpp[256+tid] + qpp[512+tid] + qpp[768+tid];
    else if (tid < 288) x0[tid] = h0[b*Dz + s*32 + (tid-256)];
  }
  __syncthreads();
  if (tid == 0){
    __builtin_amdgcn_fence(__ATOMIC_RELEASE, "agent");
    __hip_atomic_store(flags + b*8 + s, 1u, __ATOMIC_RELAXED, __HIP_MEMORY_SCOPE_AGENT);
  }

  const float bv0 = bv[0];
  const int ss = tid >> 3, p8 = tid & 7;

  for (int t = 0; t < Tz; ++t){
    // ---- poll peers (token t+1 = step-t inputs ready in parity t&1) ----
    if (tid < 64){
      const unsigned tgt = (unsigned)(t+1);
      while (__hip_atomic_load(flags + b*8 + (tid & 7), __ATOMIC_RELAXED, __HIP_MEMORY_SCOPE_AGENT) < tgt)
        __builtin_amdgcn_s_sleep(1);
      __builtin_amdgcn_fence(__ATOMIC_ACQUIRE, "agent");
    }
    __syncthreads();
    const float* xcp = xch + (size_t)((t & 1)*256 + b*8)*288;
    // ---- assemble q, x=[emb||h] ----
    if (tid < 256){
      float q = bq[tid];
      #pragma unroll
      for (int s2 = 0; s2 < 8; ++s2) q += xcp[s2*288 + tid];
      qv[tid] = q;
    } else if (tid < 512){
      int u = tid - 256;
      xe[256 + u] = xcp[(u >> 5)*288 + 256 + (u & 31)];
    } else if (tid < 768){
      int eidx = tid - 512;
      int tk = tok[b*Tz + t];
      xe[eidx] = Emb[(size_t)tk*Dz + eidx];
    }
    __syncthreads();
    // ---- scores (redundant, all 128 s): 8 threads per s ----
    {
      const float* kp = keys + (size_t)(b*Sz + ss)*Dz;
      float a = 0.f;
      #pragma unroll
      for (int j4 = 0; j4 < 8; ++j4){
        const int d0 = j4*32 + p8*4;          // lanes p8 contiguous 128B -> coalesced
        float4 kv = *(const float4*)(kp + d0);
        float4 qj = *(const float4*)(qv + d0);
        float4 vj = *(const float4*)(vl + d0);
        a += tanhfast(qj.x + kv.x) * vj.x;
        a += tanhfast(qj.y + kv.y) * vj.y;
        a += tanhfast(qj.z + kv.z) * vj.z;
        a += tanhfast(qj.w + kv.w) * vj.w;
      }
      a += __shfl_down(a, 4);
      a += __shfl_down(a, 2);
      a += __shfl_down(a, 1);
      if (p8 == 0) scp[ss] = a;
    }
    __syncthreads();
    if (tid < Sz) selds[tid] = __expf(scp[tid] + bv0);
    __syncthreads();
    if (tid < 64){
      float v = selds[tid] + selds[tid+64];
      #pragma unroll
      for (int off = 32; off > 0; off >>= 1) v += __shfl_down(v, off);
      if (tid == 0) selds[Sz] = 1.0f / v;
    }
    __syncthreads();
    // ---- z partials: register weights x LDS-broadcast x  +  encW attention part ----
    {
      float acc1 = 0.f;
      const float* xep = xe + kc*64;
      #pragma unroll
      for (int i4 = 0; i4 < 16; ++i4){
        float4 xv = *(const float4*)(xep + i4*4);
        acc1 += xv.x*w[i4*4+0] + xv.y*w[i4*4+1] + xv.z*w[i4*4+2] + xv.w*w[i4*4+3];
      }
      float acc2 = 0.f;
      const float* ewp = encW + (size_t)(b*Sz + kc*16)*1024 + u_gate;
      #pragma unroll
      for (int m = 0; m < 16; ++m)
        acc2 = __builtin_fmaf(selds[kc*16 + m], ewp[(size_t)m*1024], acc2);
      zp[kc*128 + u_local] = acc1 + selds[Sz]*acc2;
    }
    __syncthreads();
    if (tid < 128){
      float z = bl[((tid >> 5) << 8) + s*32 + (tid & 31)];
      #pragma unroll
      for (int k2 = 0; k2 < 8; ++k2) z += zp[k2*128 + tid];
      zl[tid] = z;
    }
    __syncthreads();
    if (tid < 32){
      float zi = zl[tid], zf = zl[32+tid], zg = zl[64+tid], zo = zl[96+tid];
      float cn = sigmf(zf)*clds[tid] + sigmf(zi)*tanhfast(zg);
      float hn = sigmf(zo)*tanhfast(cn);
      clds[tid] = cn; hnl[tid] = hn;
      hs[(size_t)(t*Bz + b)*Dz + s*32 + tid] = hn;
    }
    __syncthreads();
    // ---- publish next-step exchange ----
    if (t < Tz-1){
      {
        float qp = 0.f;
        #pragma unroll
        for (int jj = 0; jj < 8; ++jj) qp += hnl[jc*8 + jj] * wq[jj];
        qpp[jc*256 + dq] = qp;
      }
      __syncthreads();
      {
        float* xn = xch + (size_t)(((t+1) & 1)*256 + b*8 + s)*288;
        if (tid < 256)      xn[tid] = qpp[tid] + qpp[256+tid] + qpp[512+tid] + qpp[768+tid];
        else if (tid < 288) xn[tid] = hnl[tid - 256];
      }
      __syncthreads();
      if (tid == 0){
        __builtin_amdgcn_fence(__ATOMIC_RELEASE, "agent");
        __hip_atomic_store(flags + b*8 + s, (unsigned)(t+2), __ATOMIC_RELAXED, __HIP_MEMORY_SCOPE_AGENT);
      }
    }
  }
}

// ---------------- K3: out = exp(hs @ Wo + bo), tiled GEMM; row-sum partials -> part -----------
// grid (250, 16), 256 thr. C-tile 128x128, thread-tile 8x8, LDS-staged A^T and B.
__global__ void __launch_bounds__(256) k_logits(
    const float* __restrict__ hs, const float* __restrict__ Wo, const float* __restrict__ bo,
    float* __restrict__ out, float* __restrict__ part)
{
  __shared__ float As[32][132];   // [k][row], padded
  __shared__ float Bs[32][132];   // [k][col], padded
  __shared__ float rs[128][17];
  const int tid = threadIdx.x;
  const int c0 = blockIdx.x * 128;
  const int R0 = blockIdx.y * 128;
  const int ty = tid >> 4;        // 0..15
  const int tx = tid & 15;        // 0..15
  float acc[8][8];
  #pragma unroll
  for (int i = 0; i < 8; ++i)
    #pragma unroll
    for (int j = 0; j < 8; ++j) acc[i][j] = 0.f;

  for (int k0 = 0; k0 < Dz; k0 += 32){
    #pragma unroll
    for (int i = 0; i < 4; ++i){          // stage A: 128r x 32k (transpose to [k][r])
      int idx = tid + i*256;              // float4 id
      int r = idx >> 3, cq = idx & 7;
      float4 hv = *(const float4*)(hs + (size_t)(R0 + r)*Dz + k0 + cq*4);
      As[cq*4+0][r] = hv.x; As[cq*4+1][r] = hv.y; As[cq*4+2][r] = hv.z; As[cq*4+3][r] = hv.w;
    }
    #pragma unroll
    for (int i = 0; i < 4; ++i){          // stage B: 32k x 128c
      int idx = tid + i*256;
      int kk = idx >> 5, c4 = idx & 31;
      float4 wv = *(const float4*)(Wo + (size_t)(k0 + kk)*Vz + c0 + c4*4);
      *(float4*)(&Bs[kk][c4*4]) = wv;
    }
    __syncthreads();
    #pragma unroll
    for (int kk = 0; kk < 32; ++kk){
      float4 a0 = *(const float4*)(&As[kk][ty*8]);
      float4 a1 = *(const float4*)(&As[kk][ty*8+4]);
      float a[8] = {a0.x,a0.y,a0.z,a0.w,a1.x,a1.y,a1.z,a1.w};
      float bb[8];
      #pragma unroll
      for (int j = 0; j < 8; ++j) bb[j] = Bs[kk][tx + 16*j];   // interleaved cols: conflict-free
      #pragma unroll
      for (int i = 0; i < 8; ++i)
        #pragma unroll
        for (int j = 0; j < 8; ++j)
          acc[i][j] = __builtin_fmaf(a[i], bb[j], acc[i][j]);
    }
    __syncthreads();
  }
  // epilogue: exp, store, row-sums
  float rsum_loc[8];
  #pragma unroll
  for (int i = 0; i < 8; ++i) rsum_loc[i] = 0.f;
  #pragma unroll
  for (int i = 0; i < 8; ++i){
    const int R = R0 + ty*8 + i;
    const int orow = (R & 31)*64 + (R >> 5);   // R = t*32+b -> out row b*64+t
    float* orp = out + (size_t)orow*Vz + c0;
    #pragma unroll
    for (int j = 0; j < 8; ++j){
      const int col = tx + 16*j;
      float p = __expf(acc[i][j] + bo[c0 + col]);
      orp[col] = p;
      rsum_loc[i] += p;
    }
  }
  #pragma unroll
  for (int i = 0; i < 8; ++i) rs[ty*8+i][tx] = rsum_loc[i];
  __syncthreads();
  if (tid < 128){
    float ssum = 0.f;
    #pragma unroll
    for (int x = 0; x < 16; ++x) ssum += rs[tid][x];
    part[(size_t)blockIdx.x*2048 + R0 + tid] = ssum;
  }
}

// ---------------- K4: row-sum over 250 col-blocks + out *= 1/sum ----------------
__global__ void __launch_bounds__(256) k_scale(float* __restrict__ out, const float* __restrict__ part){
  const int row = blockIdx.x;              // out-row = b*64 + t
  const int b = row >> 6, tt = row & 63;
  const int R = tt*Bz + b;
  const int tid = threadIdx.x;
  __shared__ float ssum[4];
  float v = (tid < 250) ? part[(size_t)tid*2048 + R] : 0.f;
  #pragma unroll
  for (int off = 32; off > 0; off >>= 1) v += __shfl_down(v, off);
  if ((tid & 63) == 0) ssum[tid >> 6] = v;
  __syncthreads();
  const float inv = 1.0f / (ssum[0] + ssum[1] + ssum[2] + ssum[3]);
  float4* rp = (float4*)(out + (size_t)row*Vz);
  for (int j4 = tid; j4 < Vz/4; j4 += 256){
    float4 x = rp[j4];
    x.x *= inv; x.y *= inv; x.z *= inv; x.w *= inv;
    rp[j4] = x;
  }
}

extern "C" void kernel_launch(void* const* d_in, const int* in_sizes, int n_in,
                              void* d_out, int out_size, void* d_ws, size_t ws_size,
                              hipStream_t stream){
  const int*   tok = (const int*)  d_in[0];
  const float* h0  = (const float*)d_in[1];
  const float* c0  = (const float*)d_in[2];
  const float* enc = (const float*)d_in[3];
  const float* E   = (const float*)d_in[4];
  const float* Wq  = (const float*)d_in[5];
  const float* bq  = (const float*)d_in[6];
  const float* Wk  = (const float*)d_in[7];
  const float* bk  = (const float*)d_in[8];
  const float* Vw  = (const float*)d_in[9];
  const float* bv  = (const float*)d_in[10];
  const float* Wx  = (const float*)d_in[11];
  const float* Wh  = (const float*)d_in[12];
  const float* bl  = (const float*)d_in[13];
  const float* Wo  = (const float*)d_in[14];
  const float* bo  = (const float*)d_in[15];
  float* out = (float*)d_out;
  float* ws  = (float*)d_ws;

  float* keys = ws;                        // 1,048,576 f
  float* encW = keys + 1048576;            // 4,194,304 f  (32*128*1024)
  float* hs   = encW + 4194304;            //   524,288 f
  float* xchg = hs   + 524288;             //   147,456 f  (2*32*8*288)
  unsigned* flags = (unsigned*)(xchg + 147456);  // 256 u32
  float* part = encW;                      // alias: part (250*2048) used only after k_recur

  hipLaunchKernelGGL(k_keys, dim3(256), dim3(256), 0, stream, enc, Wk, bk, keys);
  hipLaunchKernelGGL(k_encw, dim3(1024), dim3(256), 0, stream, enc, Wx, encW, flags);
  hipLaunchKernelGGL(k_recur, dim3(256), dim3(1024), 0, stream,
                     tok, h0, c0, E, Wq, bq, Vw, bv, Wx, Wh, bl, keys, encW,
                     hs, xchg, flags);
  hipLaunchKernelGGL(k_logits, dim3(250,16), dim3(256), 0, stream, hs, Wo, bo, out, part);
  hipLaunchKernelGGL(k_scale, dim3(2048), dim3(256), 0, stream, out, part);
}

// Round 5
// 1479.211 us; speedup vs baseline: 6.6484x; 1.4361x over previous
//
#include <hip/hip_runtime.h>

#define Bz 32
#define Tz 64
#define Sz 128
#define Dz 256
#define Vz 32000

__device__ __forceinline__ float sigmf(float x){ return 1.0f/(1.0f + __expf(-x)); }
__device__ __forceinline__ float tanhfast(float x){ float e = __expf(2.0f*x); return 1.0f - 2.0f/(e+1.0f); }

// ---------------- K1: keys = enc_out @ Wk + bk  ([32,128,256]) ----------------
__global__ void k_keys(const float* __restrict__ enc, const float* __restrict__ Wk,
                       const float* __restrict__ bk, float* __restrict__ keys){
  const int blk = blockIdx.x;   // 256 blocks = 32 b x 8 s-chunks
  const int tid = threadIdx.x;  // 256
  const int b  = blk >> 3;
  const int s0 = (blk & 7) * 16;
  const float* ebase = enc + (b*Sz + s0)*Dz;
  const int d = tid;
  float acc[16];
  #pragma unroll
  for (int i = 0; i < 16; ++i) acc[i] = 0.f;
  for (int k = 0; k < Dz; k += 4){
    float w0 = Wk[(k+0)*Dz + d];
    float w1 = Wk[(k+1)*Dz + d];
    float w2 = Wk[(k+2)*Dz + d];
    float w3 = Wk[(k+3)*Dz + d];
    #pragma unroll
    for (int si = 0; si < 16; ++si){
      float4 ev = *(const float4*)(ebase + si*Dz + k);
      acc[si] += ev.x*w0 + ev.y*w1 + ev.z*w2 + ev.w*w3;
    }
  }
  const float bkd = bk[d];
  #pragma unroll
  for (int si = 0; si < 16; ++si)
    keys[(b*Sz + s0 + si)*Dz + d] = acc[si] + bkd;
}

// ---------------- K1b: encW[b*128+s][1024] = enc[b,s,:] @ Wx[0:256,:]  (+ flag reset) --------
__global__ void __launch_bounds__(256) k_encw(const float* __restrict__ enc,
                                              const float* __restrict__ Wx,
                                              float* __restrict__ encW,
                                              unsigned* flags){
  const int tid = threadIdx.x;
  if (blockIdx.x == 0) flags[tid] = 0u;     // reset barrier flags (kernel boundary publishes)
  const int row0 = blockIdx.x * 4;          // 1024 blocks x 4 rows = 4096 rows
  const int u4 = tid * 4;
  float4 a0 = {0,0,0,0}, a1 = {0,0,0,0}, a2 = {0,0,0,0}, a3 = {0,0,0,0};
  for (int d = 0; d < Dz; ++d){
    float4 wv = *(const float4*)(Wx + (size_t)d*1024 + u4);
    float e0 = enc[(size_t)(row0+0)*Dz + d];
    float e1 = enc[(size_t)(row0+1)*Dz + d];
    float e2 = enc[(size_t)(row0+2)*Dz + d];
    float e3 = enc[(size_t)(row0+3)*Dz + d];
    a0.x += e0*wv.x; a0.y += e0*wv.y; a0.z += e0*wv.z; a0.w += e0*wv.w;
    a1.x += e1*wv.x; a1.y += e1*wv.y; a1.z += e1*wv.z; a1.w += e1*wv.w;
    a2.x += e2*wv.x; a2.y += e2*wv.y; a2.z += e2*wv.z; a2.w += e2*wv.w;
    a3.x += e3*wv.x; a3.y += e3*wv.y; a3.z += e3*wv.z; a3.w += e3*wv.w;
  }
  *(float4*)(encW + (size_t)(row0+0)*1024 + u4) = a0;
  *(float4*)(encW + (size_t)(row0+1)*1024 + u4) = a1;
  *(float4*)(encW + (size_t)(row0+2)*1024 + u4) = a2;
  *(float4*)(encW + (size_t)(row0+3)*1024 + u4) = a3;
}

// ---------------- K2: recurrence. 256 blocks = 32 rows x 8 unit-slices, 1024 thr ----------------
// ZERO agent-scope fences in the step loop: all cross-block data (xch, flags) moves via
// agent-scope RELAXED ATOMIC loads/stores, which bypass L1/L2 to the coherent L3.
//   write: atomic stores -> __syncthreads (drains each wave's vmcnt, stores ack'd at L3)
//          -> tid0 relaxed flag store.
//   read:  relaxed flag poll -> workgroup acquire fence (waitcnt only, NO cache inv)
//          -> atomic data loads.
// L2 stays warm across all 64 steps (r4's 17 MB/step refetch was the agent-acquire L2 inv).
// encW slice (64 KB) additionally staged in LDS once (grid = 256 = #CUs, 1 block/CU).
__global__ void __launch_bounds__(1024) k_recur(
    const int* __restrict__ tok, const float* __restrict__ h0, const float* __restrict__ c0,
    const float* __restrict__ Emb,
    const float* __restrict__ Wq, const float* __restrict__ bq,
    const float* __restrict__ Vw, const float* __restrict__ bv,
    const float* __restrict__ Wx, const float* __restrict__ Wh,
    const float* __restrict__ bl, const float* __restrict__ keys,
    const float* __restrict__ encW,
    float* __restrict__ hs, float* xch, unsigned* flags)
{
  const int tid = threadIdx.x;
  const int blk = blockIdx.x;
  const int b = ((blk >> 6) << 3) | (blk & 7);   // row
  const int s = (blk >> 3) & 7;                  // unit-slice

  __shared__ float ew[Sz*128];     // encW slice [s(128)][u_local(128)] = 64 KB
  __shared__ float xe[512];        // [emb(256) || h(256)]
  __shared__ float qv[Dz];
  __shared__ float vl[Dz];
  __shared__ float scp[Sz];
  __shared__ float selds[Sz+1];
  __shared__ float zp[1024];       // [kc(8)][u_local(128)]
  __shared__ float zl[128];
  __shared__ float hnl[32];
  __shared__ float clds[32];
  __shared__ float qpp[1024];      // [jc(4)][d(256)]

  const int u_local = tid & 127;
  const int kc = tid >> 7;                                   // 0..7
  const int u_gate = ((u_local >> 5) << 8) + (s << 5) + (u_local & 31);
  const int dq = tid & 255;                                  // q-part d
  const int jc = tid >> 8;                                   // 0..3

  // --- one-time loads ---
  float w[64];   // gate weights, k_x = kc*64+i over [emb(0..255)||h(256..511)]
  {
    const float* wbase = (kc < 4) ? (Wx + (size_t)(256 + kc*64)*1024 + u_gate)
                                  : (Wh + (size_t)((kc-4)*64)*1024 + u_gate);
    #pragma unroll
    for (int i = 0; i < 64; ++i) w[i] = wbase[(size_t)i*1024];
  }
  float wq[8];   // Wq rows [32s+jc*8 .. +8), col dq
  #pragma unroll
  for (int jj = 0; jj < 8; ++jj) wq[jj] = Wq[(size_t)(s*32 + jc*8 + jj)*Dz + dq];

  // --- stage this block's encW slice into LDS (rows: all 128 s; cols: its 128 u_gate) ---
  #pragma unroll
  for (int i = 0; i < 16; ++i){
    int idx = tid + i*1024;
    int srow = idx >> 7, ul = idx & 127;
    int ug = ((ul >> 5) << 8) + (s << 5) + (ul & 31);
    ew[idx] = encW[(size_t)(b*Sz + srow)*1024 + ug];
  }

  if (tid < Dz) vl[tid] = Vw[tid];
  if (tid < 32) clds[tid] = c0[b*Dz + s*32 + tid];

  // --- pre-exchange (t=0 inputs from h0) ---
  {
    float qp = 0.f;
    #pragma unroll
    for (int jj = 0; jj < 8; ++jj) qp += h0[b*Dz + s*32 + jc*8 + jj] * wq[jj];
    qpp[jc*256 + dq] = qp;
  }
  __syncthreads();
  {
    float* x0 = xch + (size_t)((b*8) + s)*288;   // parity 0
    if (tid < 256)
      __hip_atomic_store(x0 + tid, qpp[tid] + qpp[256+tid] + qpp[512+tid] + qpp[768+tid],
                         __ATOMIC_RELAXED, __HIP_MEMORY_SCOPE_AGENT);
    else if (tid < 288)
      __hip_atomic_store(x0 + tid, h0[b*Dz + s*32 + (tid-256)],
                         __ATOMIC_RELAXED, __HIP_MEMORY_SCOPE_AGENT);
  }
  __syncthreads();   // all waves' atomic stores ack'd at L3
  if (tid == 0)
    __hip_atomic_store(flags + b*8 + s, 1u, __ATOMIC_RELAXED, __HIP_MEMORY_SCOPE_AGENT);

  const float bv0 = bv[0];
  const int ss = tid >> 3, p8 = tid & 7;

  for (int t = 0; t < Tz; ++t){
    // ---- poll peers (token t+1 = step-t inputs ready in parity t&1) ----
    if (tid < 64){
      const unsigned tgt = (unsigned)(t+1);
      while (__hip_atomic_load(flags + b*8 + (tid & 7), __ATOMIC_RELAXED, __HIP_MEMORY_SCOPE_AGENT) < tgt)
        __builtin_amdgcn_s_sleep(1);
      __builtin_amdgcn_fence(__ATOMIC_ACQUIRE, "workgroup");   // ordering only, no cache inv
    }
    __syncthreads();
    const float* xcp = xch + (size_t)((t & 1)*256 + b*8)*288;
    // ---- assemble q, x=[emb||h] (atomic bypass loads: L1/L2 may be stale for xch) ----
    if (tid < 256){
      float q = bq[tid];
      #pragma unroll
      for (int s2 = 0; s2 < 8; ++s2)
        q += __hip_atomic_load(xcp + s2*288 + tid, __ATOMIC_RELAXED, __HIP_MEMORY_SCOPE_AGENT);
      qv[tid] = q;
    } else if (tid < 512){
      int u = tid - 256;
      xe[256 + u] = __hip_atomic_load(xcp + (u >> 5)*288 + 256 + (u & 31),
                                      __ATOMIC_RELAXED, __HIP_MEMORY_SCOPE_AGENT);
    } else if (tid < 768){
      int eidx = tid - 512;
      int tk = tok[b*Tz + t];
      xe[eidx] = Emb[(size_t)tk*Dz + eidx];
    }
    __syncthreads();
    // ---- scores (redundant, all 128 s): 8 threads per s ----
    {
      const float* kp = keys + (size_t)(b*Sz + ss)*Dz;
      float a = 0.f;
      #pragma unroll
      for (int j4 = 0; j4 < 8; ++j4){
        const int d0 = j4*32 + p8*4;
        float4 kv = *(const float4*)(kp + d0);
        float4 qj = *(const float4*)(qv + d0);
        float4 vj = *(const float4*)(vl + d0);
        a += tanhfast(qj.x + kv.x) * vj.x;
        a += tanhfast(qj.y + kv.y) * vj.y;
        a += tanhfast(qj.z + kv.z) * vj.z;
        a += tanhfast(qj.w + kv.w) * vj.w;
      }
      a += __shfl_down(a, 4);
      a += __shfl_down(a, 2);
      a += __shfl_down(a, 1);
      if (p8 == 0) scp[ss] = a;
    }
    __syncthreads();
    if (tid < Sz) selds[tid] = __expf(scp[tid] + bv0);
    __syncthreads();
    if (tid < 64){
      float v = selds[tid] + selds[tid+64];
      #pragma unroll
      for (int off = 32; off > 0; off >>= 1) v += __shfl_down(v, off);
      if (tid == 0) selds[Sz] = 1.0f / v;
    }
    __syncthreads();
    // ---- z partials: register weights x LDS x  +  LDS-staged encW attention part ----
    {
      float acc1 = 0.f;
      const float* xep = xe + kc*64;
      #pragma unroll
      for (int i4 = 0; i4 < 16; ++i4){
        float4 xv = *(const float4*)(xep + i4*4);
        acc1 += xv.x*w[i4*4+0] + xv.y*w[i4*4+1] + xv.z*w[i4*4+2] + xv.w*w[i4*4+3];
      }
      float acc2 = 0.f;
      const float* ewp = ew + kc*16*128 + u_local;
      #pragma unroll
      for (int m = 0; m < 16; ++m)
        acc2 = __builtin_fmaf(selds[kc*16 + m], ewp[m*128], acc2);
      zp[kc*128 + u_local] = acc1 + selds[Sz]*acc2;
    }
    __syncthreads();
    if (tid < 128){
      float z = bl[((tid >> 5) << 8) + s*32 + (tid & 31)];
      #pragma unroll
      for (int k2 = 0; k2 < 8; ++k2) z += zp[k2*128 + tid];
      zl[tid] = z;
    }
    __syncthreads();
    if (tid < 32){
      float zi = zl[tid], zf = zl[32+tid], zg = zl[64+tid], zo = zl[96+tid];
      float cn = sigmf(zf)*clds[tid] + sigmf(zi)*tanhfast(zg);
      float hn = sigmf(zo)*tanhfast(cn);
      clds[tid] = cn; hnl[tid] = hn;
      hs[(size_t)(t*Bz + b)*Dz + s*32 + tid] = hn;
    }
    __syncthreads();
    // ---- publish next-step exchange ----
    if (t < Tz-1){
      {
        float qp = 0.f;
        #pragma unroll
        for (int jj = 0; jj < 8; ++jj) qp += hnl[jc*8 + jj] * wq[jj];
        qpp[jc*256 + dq] = qp;
      }
      __syncthreads();
      {
        float* xn = xch + (size_t)(((t+1) & 1)*256 + b*8 + s)*288;
        if (tid < 256)
          __hip_atomic_store(xn + tid, qpp[tid] + qpp[256+tid] + qpp[512+tid] + qpp[768+tid],
                             __ATOMIC_RELAXED, __HIP_MEMORY_SCOPE_AGENT);
        else if (tid < 288)
          __hip_atomic_store(xn + tid, hnl[tid - 256],
                             __ATOMIC_RELAXED, __HIP_MEMORY_SCOPE_AGENT);
      }
      __syncthreads();   // all waves' atomic stores ack'd at L3
      if (tid == 0)
        __hip_atomic_store(flags + b*8 + s, (unsigned)(t+2), __ATOMIC_RELAXED, __HIP_MEMORY_SCOPE_AGENT);
    }
  }
}

// ---------------- K3: out = exp(hs @ Wo + bo), tiled GEMM; row-sum partials -> part -----------
__global__ void __launch_bounds__(256) k_logits(
    const float* __restrict__ hs, const float* __restrict__ Wo, const float* __restrict__ bo,
    float* __restrict__ out, float* __restrict__ part)
{
  __shared__ float As[32][132];   // [k][row], padded
  __shared__ float Bs[32][132];   // [k][col], padded
  __shared__ float rs[128][17];
  const int tid = threadIdx.x;
  const int c0 = blockIdx.x * 128;
  const int R0 = blockIdx.y * 128;
  const int ty = tid >> 4;        // 0..15
  const int tx = tid & 15;        // 0..15
  float acc[8][8];
  #pragma unroll
  for (int i = 0; i < 8; ++i)
    #pragma unroll
    for (int j = 0; j < 8; ++j) acc[i][j] = 0.f;

  for (int k0 = 0; k0 < Dz; k0 += 32){
    #pragma unroll
    for (int i = 0; i < 4; ++i){          // stage A: 128r x 32k (transpose to [k][r])
      int idx = tid + i*256;              // float4 id
      int r = idx >> 3, cq = idx & 7;
      float4 hv = *(const float4*)(hs + (size_t)(R0 + r)*Dz + k0 + cq*4);
      As[cq*4+0][r] = hv.x; As[cq*4+1][r] = hv.y; As[cq*4+2][r] = hv.z; As[cq*4+3][r] = hv.w;
    }
    #pragma unroll
    for (int i = 0; i < 4; ++i){          // stage B: 32k x 128c
      int idx = tid + i*256;
      int kk = idx >> 5, c4 = idx & 31;
      float4 wv = *(const float4*)(Wo + (size_t)(k0 + kk)*Vz + c0 + c4*4);
      *(float4*)(&Bs[kk][c4*4]) = wv;
    }
    __syncthreads();
    #pragma unroll
    for (int kk = 0; kk < 32; ++kk){
      float4 a0 = *(const float4*)(&As[kk][ty*8]);
      float4 a1 = *(const float4*)(&As[kk][ty*8+4]);
      float a[8] = {a0.x,a0.y,a0.z,a0.w,a1.x,a1.y,a1.z,a1.w};
      float bb[8];
      #pragma unroll
      for (int j = 0; j < 8; ++j) bb[j] = Bs[kk][tx + 16*j];
      #pragma unroll
      for (int i = 0; i < 8; ++i)
        #pragma unroll
        for (int j = 0; j < 8; ++j)
          acc[i][j] = __builtin_fmaf(a[i], bb[j], acc[i][j]);
    }
    __syncthreads();
  }
  float rsum_loc[8];
  #pragma unroll
  for (int i = 0; i < 8; ++i) rsum_loc[i] = 0.f;
  #pragma unroll
  for (int i = 0; i < 8; ++i){
    const int R = R0 + ty*8 + i;
    const int orow = (R & 31)*64 + (R >> 5);   // R = t*32+b -> out row b*64+t
    float* orp = out + (size_t)orow*Vz + c0;
    #pragma unroll
    for (int j = 0; j < 8; ++j){
      const int col = tx + 16*j;
      float p = __expf(acc[i][j] + bo[c0 + col]);
      orp[col] = p;
      rsum_loc[i] += p;
    }
  }
  #pragma unroll
  for (int i = 0; i < 8; ++i) rs[ty*8+i][tx] = rsum_loc[i];
  __syncthreads();
  if (tid < 128){
    float ssum = 0.f;
    #pragma unroll
    for (int x = 0; x < 16; ++x) ssum += rs[tid][x];
    part[(size_t)blockIdx.x*2048 + R0 + tid] = ssum;
  }
}

// ---------------- K4: row-sum over 250 col-blocks + out *= 1/sum ----------------
__global__ void __launch_bounds__(256) k_scale(float* __restrict__ out, const float* __restrict__ part){
  const int row = blockIdx.x;              // out-row = b*64 + t
  const int b = row >> 6, tt = row & 63;
  const int R = tt*Bz + b;
  const int tid = threadIdx.x;
  __shared__ float ssum[4];
  float v = (tid < 250) ? part[(size_t)tid*2048 + R] : 0.f;
  #pragma unroll
  for (int off = 32; off > 0; off >>= 1) v += __shfl_down(v, off);
  if ((tid & 63) == 0) ssum[tid >> 6] = v;
  __syncthreads();
  const float inv = 1.0f / (ssum[0] + ssum[1] + ssum[2] + ssum[3]);
  float4* rp = (float4*)(out + (size_t)row*Vz);
  for (int j4 = tid; j4 < Vz/4; j4 += 256){
    float4 x = rp[j4];
    x.x *= inv; x.y *= inv; x.z *= inv; x.w *= inv;
    rp[j4] = x;
  }
}

extern "C" void kernel_launch(void* const* d_in, const int* in_sizes, int n_in,
                              void* d_out, int out_size, void* d_ws, size_t ws_size,
                              hipStream_t stream){
  const int*   tok = (const int*)  d_in[0];
  const float* h0  = (const float*)d_in[1];
  const float* c0  = (const float*)d_in[2];
  const float* enc = (const float*)d_in[3];
  const float* E   = (const float*)d_in[4];
  const float* Wq  = (const float*)d_in[5];
  const float* bq  = (const float*)d_in[6];
  const float* Wk  = (const float*)d_in[7];
  const float* bk  = (const float*)d_in[8];
  const float* Vw  = (const float*)d_in[9];
  const float* bv  = (const float*)d_in[10];
  const float* Wx  = (const float*)d_in[11];
  const float* Wh  = (const float*)d_in[12];
  const float* bl  = (const float*)d_in[13];
  const float* Wo  = (const float*)d_in[14];
  const float* bo  = (const float*)d_in[15];
  float* out = (float*)d_out;
  float* ws  = (float*)d_ws;

  float* keys = ws;                        // 1,048,576 f
  float* encW = keys + 1048576;            // 4,194,304 f  (32*128*1024)
  float* hs   = encW + 4194304;            //   524,288 f
  float* xchg = hs   + 524288;             //   147,456 f  (2*32*8*288)
  unsigned* flags = (unsigned*)(xchg + 147456);  // 256 u32
  float* part = encW;                      // alias: part (250*2048) used only after k_recur

  hipLaunchKernelGGL(k_keys, dim3(256), dim3(256), 0, stream, enc, Wk, bk, keys);
  hipLaunchKernelGGL(k_encw, dim3(1024), dim3(256), 0, stream, enc, Wx, encW, flags);
  hipLaunchKernelGGL(k_recur, dim3(256), dim3(1024), 0, stream,
                     tok, h0, c0, E, Wq, bq, Vw, bv, Wx, Wh, bl, keys, encW,
                     hs, xchg, flags);
  hipLaunchKernelGGL(k_logits, dim3(250,16), dim3(256), 0, stream, hs, Wo, bo, out, part);
  hipLaunchKernelGGL(k_scale, dim3(2048), dim3(256), 0, stream, out, part);
}